// Round 13
// baseline (175.447 us; speedup 1.0000x reference)
//
#include <hip/hip_runtime.h>
#include <hip/hip_bf16.h>

// Flash-attention fwd, fp32 in/out, bf16 MFMA compute.
// B=64, L=1024, D=64. scale=1/sqrt(512). mask(int32)!=0 -> -1e9.
// R13 = R12 split-K structure + REAL prefetch:
//  - K/V regs for t+1 issued at body top, pinned by sched_barrier(0),
//    written to the idle LDS buffer at body bottom (T14 split)
//  - mask prefetched 2 tiles deep (static mr0/mr1 naming)
//  - per-half double-buffered K/V -> ONE barrier per tile (74 KB, 2 blk/CU)
//  - gentle __launch_bounds__(512,2): do NOT let the compiler re-sink loads
//  - compute core unchanged (swapped QK^T, in-reg P exchange, defer-max)

typedef __attribute__((ext_vector_type(4))) float f32x4;
typedef __attribute__((ext_vector_type(8))) short bf16x8;
typedef __attribute__((ext_vector_type(4))) short short4v;

constexpr int B_ = 64;
constexpr int L_ = 1024;
constexpr int D_ = 64;
constexpr int QBLK = 64;     // q rows per block (8 waves = 2 halves x 4)
constexpr int KV = 64;       // keys per tile
constexpr int NT_H = 8;      // tiles per half (split-K)
constexpr int STR = 72;      // shorts per LDS row (64 + 8 pad)
constexpr float SC2 = 0.06376003f;   // (1/sqrt(512)) * log2(e)
constexpr float NEG = -1e9f;
constexpr float THR = 8.0f;

constexpr int HBUF    = 64 * STR * 2;   // 9216 B: one K or V^T tile
constexpr int HALFREG = 4 * HBUF;       // 36864 B per half (2 bufs x (K|V))

__device__ inline short f2bf(float f) {
  __hip_bfloat16 h = __float2bfloat16(f);
  short s; __builtin_memcpy(&s, &h, 2);
  return s;
}
__device__ inline unsigned int pk2(float a, float b) {
  return (unsigned int)(unsigned short)f2bf(a)
       | ((unsigned int)(unsigned short)f2bf(b) << 16);
}

__global__ __launch_bounds__(512, 2) void attn_fwd(
    const float* __restrict__ Q, const float* __restrict__ K,
    const float* __restrict__ V, const int* __restrict__ M,
    float* __restrict__ O)
{
  // [half][buf][K 9216 | V^T 9216] = 73728 B + 512 B combine tail
  __shared__ __align__(16) unsigned char smem[2 * HALFREG + 512];

  const int tid  = threadIdx.x;
  const int w    = tid >> 6;        // 0..7
  const int half = w >> 2;          // 0: keys 0-511, 1: keys 512-1023
  const int w4   = w & 3;           // wave within half; q-rows w4*16..+15
  const int lane = tid & 63;
  const int g    = lane >> 4;
  const int c    = lane & 15;
  const int htid = tid & 255;       // thread id within half
  const int b    = blockIdx.y;
  const int q0   = blockIdx.x * QBLK;

  auto k_base  = [&](int buf) {
    return (short(*)[STR])(smem + half * HALFREG + buf * (2 * HBUF));
  };
  auto vt_base = [&](int buf) {
    return (short(*)[STR])(smem + half * HALFREG + buf * (2 * HBUF) + HBUF);
  };

  // ---- Q fragment (B operand of swapped QK^T): col=c -> q-row w4*16+c
  bf16x8 qf[2];
  {
    const float* qp = Q + ((size_t)b * L_ + q0 + w4 * 16 + c) * D_ + g * 8;
#pragma unroll
    for (int ks = 0; ks < 2; ++ks) {
      f32x4 x0 = *(const f32x4*)(qp + ks * 32);
      f32x4 x1 = *(const f32x4*)(qp + ks * 32 + 4);
      bf16x8 t;
      t[0] = f2bf(x0[0]); t[1] = f2bf(x0[1]); t[2] = f2bf(x0[2]); t[3] = f2bf(x0[3]);
      t[4] = f2bf(x1[0]); t[5] = f2bf(x1[1]); t[6] = f2bf(x1[2]); t[7] = f2bf(x1[3]);
      qf[ks] = t;
    }
  }

  const float* Kb = K + (size_t)b * L_ * D_ + (size_t)half * NT_H * KV * D_;
  const float* Vb = V + (size_t)b * L_ * D_ + (size_t)half * NT_H * KV * D_;
  const int* mlane = M + (size_t)b * L_ * L_
                   + (size_t)(q0 + w4 * 16 + c) * L_ + half * (NT_H * KV) + 4 * g;

  const int vkey4 = (htid & 15) * 4;   // V staging: 4x4 block per thread
  const int vd4   = (htid >> 4) * 4;

  f32x4 kreg[4], vreg[4];              // held across compute (pinned)
  int4  mr0[4], mr1[4];                // mask, 2 tiles deep

  auto load_kv = [&](int t) {
    const float* ksrc = Kb + (size_t)(t * KV) * D_;
    const float* vsrc = Vb + (size_t)(t * KV) * D_;
#pragma unroll
    for (int i = 0; i < 4; ++i) {
      kreg[i] = *(const f32x4*)(ksrc + (size_t)(htid + i * 256) * 4);
      vreg[i] = *(const f32x4*)(vsrc + (size_t)(vkey4 + i) * D_ + vd4);
    }
  };
  auto load_m = [&](int t, int4 (&mr)[4]) {
#pragma unroll
    for (int f = 0; f < 4; ++f)
      mr[f] = *(const int4*)(mlane + t * KV + f * 16);
  };
  auto write_kv = [&](int buf) {
    short (*kl)[STR]  = k_base(buf);
    short (*vtl)[STR] = vt_base(buf);
#pragma unroll
    for (int i = 0; i < 4; ++i) {
      const int idx = htid + i * 256;
      short4v ks4 = { f2bf(kreg[i][0]), f2bf(kreg[i][1]),
                      f2bf(kreg[i][2]), f2bf(kreg[i][3]) };
      *(short4v*)&kl[idx >> 4][(idx & 15) * 4] = ks4;
      const int jj = (i + (htid >> 4)) & 3;  // rotated row order (bank spread)
      short4v vt4 = { f2bf(vreg[0][jj]), f2bf(vreg[1][jj]),
                      f2bf(vreg[2][jj]), f2bf(vreg[3][jj]) };
      *(short4v*)&vtl[vd4 + jj][vkey4] = vt4;
    }
  };
  auto packm = [&](const int4 (&lm)[4]) {
    unsigned int mp = 0;
#pragma unroll
    for (int f = 0; f < 4; ++f) {
      mp |= (lm[f].x != 0 ? 1u : 0u) << (f * 4 + 0);
      mp |= (lm[f].y != 0 ? 1u : 0u) << (f * 4 + 1);
      mp |= (lm[f].z != 0 ? 1u : 0u) << (f * 4 + 2);
      mp |= (lm[f].w != 0 ? 1u : 0u) << (f * 4 + 3);
    }
    return mp;
  };

  f32x4 acc[4];
#pragma unroll
  for (int i = 0; i < 4; ++i) acc[i] = (f32x4){0.f, 0.f, 0.f, 0.f};
  float m_run = -INFINITY;
  float l_run = 0.f;

  // prologue: tile 0 staged; masks for tiles 0 and 1 in flight
  load_kv(0);
  write_kv(0);
  load_m(0, mr0);
  load_m(1, mr1);
  __builtin_amdgcn_sched_barrier(0);
  __syncthreads();

  auto body = [&](int t, int4 (&mr)[4]) {
    const int cur = t & 1;
    const bool has_next = (t + 1 < NT_H);
    if (has_next) load_kv(t + 1);        // issue K/V early (in flight below)
    const unsigned int mc = packm(mr);   // waits only this tile's mask loads
    if (t + 2 < NT_H) load_m(t + 2, mr); // keep mask 2 tiles deep
    __builtin_amdgcn_sched_barrier(0);   // PIN: no sinking past this point

    // ---- S^T = K Q^T : C row = key = f*16+g*4+r, col = q = c
    short (*kl)[STR]  = k_base(cur);
    short (*vtl)[STR] = vt_base(cur);
    f32x4 sc[4];
#pragma unroll
    for (int f = 0; f < 4; ++f) {
      f32x4 a = (f32x4){0.f, 0.f, 0.f, 0.f};
#pragma unroll
      for (int ks = 0; ks < 2; ++ks) {
        bf16x8 kf = *(const bf16x8*)&kl[f * 16 + c][ks * 32 + g * 8];
        a = __builtin_amdgcn_mfma_f32_16x16x32_bf16(kf, qf[ks], a, 0, 0, 0);
      }
      sc[f] = a;
    }

    // ---- mask + scale into log2 domain
#pragma unroll
    for (int f = 0; f < 4; ++f)
#pragma unroll
      for (int r = 0; r < 4; ++r)
        sc[f][r] = ((mc >> (f * 4 + r)) & 1u) ? NEG : sc[f][r] * SC2;

    // ---- online softmax with defer-max
    float xl = sc[0][0];
#pragma unroll
    for (int f = 0; f < 4; ++f)
#pragma unroll
      for (int r = 0; r < 4; ++r) xl = fmaxf(xl, sc[f][r]);
    if (!__all(xl <= m_run + THR)) {
      float x = fmaxf(xl, __shfl_xor(xl, 16, 64));
      x = fmaxf(x, __shfl_xor(x, 32, 64));
      const float m_new = fmaxf(m_run, x);
      const float alpha = exp2f(m_run - m_new);
      l_run *= alpha;
      float ar[4];
#pragma unroll
      for (int r = 0; r < 4; ++r)
        ar[r] = __shfl(alpha, (lane & 48) | (g * 4 + r), 64);
#pragma unroll
      for (int fd = 0; fd < 4; ++fd)
#pragma unroll
        for (int r = 0; r < 4; ++r) acc[fd][r] *= ar[r];
      m_run = m_new;
    }
    float s = 0.f;
#pragma unroll
    for (int f = 0; f < 4; ++f)
#pragma unroll
      for (int r = 0; r < 4; ++r) {
        const float p = exp2f(sc[f][r] - m_run);
        sc[f][r] = p;
        s += p;
      }
    l_run += s;

    // ---- P relayout C->A in-register (two matchings, verified R10)
    unsigned int pd[4][2];
#pragma unroll
    for (int f = 0; f < 4; ++f) {
      pd[f][0] = pk2(sc[f][0], sc[f][1]);
      pd[f][1] = pk2(sc[f][2], sc[f][3]);
    }
    const int rev2 = ((g & 1) << 1) | (g >> 1);
    const int srcA = rev2 * 16 + c;
    const int srcB = srcA ^ 16;
    const bool podd = (g & 1) != 0;
    const bool gh   = (g >= 2);
    unsigned int d0[4], d1[4];
#pragma unroll
    for (int k = 0; k < 4; ++k) {
      const int fb = 2 * (k >> 1);
      const int hh = k & 1;
      const unsigned int pubA = podd ? pd[fb + 1][hh] : pd[fb + 0][hh];
      const unsigned int pubB = podd ? pd[fb + 0][hh] : pd[fb + 1][hh];
      const unsigned int rvA = (unsigned int)__shfl((int)pubA, srcA, 64);
      const unsigned int rvB = (unsigned int)__shfl((int)pubB, srcB, 64);
      if (k < 2) {
        if (gh) { d0[2 + hh] = rvA; d0[hh] = rvB; }
        else    { d0[hh] = rvA; d0[2 + hh] = rvB; }
      } else {
        if (gh) { d1[2 + hh] = rvA; d1[hh] = rvB; }
        else    { d1[hh] = rvA; d1[2 + hh] = rvB; }
      }
    }
    bf16x8 pa0, pa1;
    __builtin_memcpy(&pa0, d0, 16);
    __builtin_memcpy(&pa1, d1, 16);

    // ---- O += P V
#pragma unroll
    for (int fd = 0; fd < 4; ++fd) {
      bf16x8 vb0 = *(const bf16x8*)&vtl[fd * 16 + c][g * 8];
      acc[fd] = __builtin_amdgcn_mfma_f32_16x16x32_bf16(pa0, vb0, acc[fd], 0, 0, 0);
      bf16x8 vb1 = *(const bf16x8*)&vtl[fd * 16 + c][32 + g * 8];
      acc[fd] = __builtin_amdgcn_mfma_f32_16x16x32_bf16(pa1, vb1, acc[fd], 0, 0, 0);
    }

    // ---- write next tile into the idle buffer; ONE barrier flips it
    if (has_next) {
      write_kv(cur ^ 1);
      __syncthreads();
    }
  };

  for (int tt = 0; tt < NT_H; tt += 2) {
    body(tt,     mr0);
    body(tt + 1, mr1);
  }

  // ==== combine the two key-halves in-block (reuse K/V LDS) ====
  float l = l_run;
  l += __shfl_xor(l, 16, 64);
  l += __shfl_xor(l, 32, 64);

  __syncthreads();                      // all compute done; LDS reusable
  f32x4* cacc = (f32x4*)smem;           // 16 KB scratch (half 0, buf 0 region)
  float2* cml = (float2*)(smem + 2 * HALFREG);
  if (half == 1) {
#pragma unroll
    for (int fd = 0; fd < 4; ++fd)
      cacc[(w4 * 64 + lane) * 4 + fd] = acc[fd];
    if (g == 0) cml[w4 * 16 + c] = make_float2(m_run, l);
  }
  __syncthreads();
  if (half == 0) {
    const float2 mlB = cml[w4 * 16 + c];
    const float Mx = fmaxf(m_run, mlB.x);
    const float wA = exp2f(m_run - Mx);
    const float wB = exp2f(mlB.x - Mx);
    const float li = 1.0f / (wA * l + wB * mlB.y);
    float arA[4], arB[4], lr[4];
#pragma unroll
    for (int r = 0; r < 4; ++r) {
      const int src = (lane & 48) | (g * 4 + r);
      arA[r] = __shfl(wA, src, 64);
      arB[r] = __shfl(wB, src, 64);
      lr[r]  = __shfl(li, src, 64);
    }
    float* orow = O + ((size_t)b * L_ + q0 + w4 * 16 + g * 4) * D_;
#pragma unroll
    for (int fd = 0; fd < 4; ++fd) {
      const f32x4 ab = cacc[(w4 * 64 + lane) * 4 + fd];
#pragma unroll
      for (int r = 0; r < 4; ++r)
        orow[(size_t)r * D_ + fd * 16 + c] =
            (arA[r] * acc[fd][r] + arB[r] * ab[r]) * lr[r];
    }
  }
}

extern "C" void kernel_launch(void* const* d_in, const int* in_sizes, int n_in,
                              void* d_out, int out_size, void* d_ws, size_t ws_size,
                              hipStream_t stream) {
  const float* q = (const float*)d_in[0];
  const float* k = (const float*)d_in[1];
  const float* v = (const float*)d_in[2];
  const int* m = (const int*)d_in[3]; // jax bool shipped as int32
  float* o = (float*)d_out;
  dim3 grid(L_ / QBLK, B_);
  attn_fwd<<<grid, 512, 0, stream>>>(q, k, v, m, o);
}

// Round 14
// 147.326 us; speedup vs baseline: 1.1909x; 1.1909x over previous
//
#include <hip/hip_runtime.h>
#include <hip/hip_bf16.h>

// Flash-attention fwd, fp32 in/out, bf16 MFMA compute.
// B=64, L=1024, D=64. scale=1/sqrt(512). mask(int32)!=0 -> -1e9.
// R14: satisfy ALL THREE occupancy caps at once + true T14 pipeline.
//  - split-K 512-thr blocks (8192 wave-jobs; grid cap gone)
//  - SINGLE K/V buffer per half: 37.4 KB -> 4 blocks/CU (LDS cap gone)
//  - VGPR diet ~<=102 -> 5 waves/SIMD -> 20 waves/CU: mask 1-deep,
//    cvt before barrier (kreg/vreg die early), no packm
//  - T14: issue loads(t+1) at top (sched_barrier pinned, in flight through
//    compute) -> compute(t) -> cvt -> barrier -> ds_writes only -> barrier
//  - compute core verified (swapped QK^T, in-reg P exchange, defer-max)

typedef __attribute__((ext_vector_type(4))) float f32x4;
typedef __attribute__((ext_vector_type(8))) short bf16x8;
typedef __attribute__((ext_vector_type(4))) short short4v;

constexpr int B_ = 64;
constexpr int L_ = 1024;
constexpr int D_ = 64;
constexpr int QBLK = 64;     // q rows per block (8 waves = 2 halves x 4)
constexpr int KV = 64;       // keys per tile
constexpr int NT_H = 8;      // tiles per half (split-K)
constexpr int STR = 72;      // shorts per LDS row (64 + 8 pad)
constexpr float SC2 = 0.06376003f;   // (1/sqrt(512)) * log2(e)
constexpr float NEG = -1e9f;
constexpr float THR = 8.0f;

constexpr int HBUF     = 64 * STR * 2;  // 9216 B: one K or V^T tile
constexpr int HALF_LDS = 2 * HBUF;      // 18432 B per half (K | V^T)

__device__ inline short f2bf(float f) {
  __hip_bfloat16 h = __float2bfloat16(f);
  short s; __builtin_memcpy(&s, &h, 2);
  return s;
}
__device__ inline unsigned int pk2(float a, float b) {
  return (unsigned int)(unsigned short)f2bf(a)
       | ((unsigned int)(unsigned short)f2bf(b) << 16);
}

__global__ __launch_bounds__(512, 2) void attn_fwd(
    const float* __restrict__ Q, const float* __restrict__ K,
    const float* __restrict__ V, const int* __restrict__ M,
    float* __restrict__ O)
{
  // [half][K 9216 | V^T 9216] = 36864 B + 512 B combine tail = 37376 B
  __shared__ __align__(16) unsigned char smem[2 * HALF_LDS + 512];

  const int tid  = threadIdx.x;
  const int w    = tid >> 6;        // 0..7
  const int half = w >> 2;          // 0: keys 0-511, 1: keys 512-1023
  const int w4   = w & 3;           // wave within half; q-rows w4*16..+15
  const int lane = tid & 63;
  const int g    = lane >> 4;
  const int c    = lane & 15;
  const int htid = tid & 255;       // thread id within half
  const int b    = blockIdx.y;
  const int q0   = blockIdx.x * QBLK;

  short (*k_lds)[STR]  = (short(*)[STR])(smem + half * HALF_LDS);
  short (*vt_lds)[STR] = (short(*)[STR])(smem + half * HALF_LDS + HBUF);

  // ---- Q fragment (B operand of swapped QK^T): col=c -> q-row w4*16+c
  bf16x8 qf[2];
  {
    const float* qp = Q + ((size_t)b * L_ + q0 + w4 * 16 + c) * D_ + g * 8;
#pragma unroll
    for (int ks = 0; ks < 2; ++ks) {
      f32x4 x0 = *(const f32x4*)(qp + ks * 32);
      f32x4 x1 = *(const f32x4*)(qp + ks * 32 + 4);
      bf16x8 t;
      t[0] = f2bf(x0[0]); t[1] = f2bf(x0[1]); t[2] = f2bf(x0[2]); t[3] = f2bf(x0[3]);
      t[4] = f2bf(x1[0]); t[5] = f2bf(x1[1]); t[6] = f2bf(x1[2]); t[7] = f2bf(x1[3]);
      qf[ks] = t;
    }
  }

  const float* Kb = K + (size_t)b * L_ * D_ + (size_t)half * NT_H * KV * D_;
  const float* Vb = V + (size_t)b * L_ * D_ + (size_t)half * NT_H * KV * D_;
  const int* mlane = M + (size_t)b * L_ * L_
                   + (size_t)(q0 + w4 * 16 + c) * L_ + half * (NT_H * KV) + 4 * g;

  const int vkey4 = (htid & 15) * 4;   // V staging: 4x4 block per thread
  const int vd4   = (htid >> 4) * 4;

  f32x4   kreg[4], vreg[4];            // fp32 in flight (die at cvt)
  short4v ksh[4], vsh[4];              // bf16, written between barriers
  int4    mr[4];                       // mask, 1 tile deep

  auto load_kv = [&](int t) {
    const float* ksrc = Kb + (size_t)(t * KV) * D_;
    const float* vsrc = Vb + (size_t)(t * KV) * D_;
#pragma unroll
    for (int i = 0; i < 4; ++i) {
      kreg[i] = *(const f32x4*)(ksrc + (size_t)(htid + i * 256) * 4);
      vreg[i] = *(const f32x4*)(vsrc + (size_t)(vkey4 + i) * D_ + vd4);
    }
  };
  auto load_m = [&](int t) {
#pragma unroll
    for (int f = 0; f < 4; ++f)
      mr[f] = *(const int4*)(mlane + t * KV + f * 16);
  };
  auto cvt_kv = [&]() {                // fp32 regs -> bf16 regs (VALU, pre-barrier)
#pragma unroll
    for (int i = 0; i < 4; ++i) {
      ksh[i] = short4v{ f2bf(kreg[i][0]), f2bf(kreg[i][1]),
                        f2bf(kreg[i][2]), f2bf(kreg[i][3]) };
      const int jj = (i + (htid >> 4)) & 3;  // rotated row order (bank spread)
      vsh[i] = short4v{ f2bf(vreg[0][jj]), f2bf(vreg[1][jj]),
                        f2bf(vreg[2][jj]), f2bf(vreg[3][jj]) };
    }
  };
  auto write_kv = [&]() {              // pure ds_writes (short barrier window)
#pragma unroll
    for (int i = 0; i < 4; ++i) {
      const int idx = htid + i * 256;
      *(short4v*)&k_lds[idx >> 4][(idx & 15) * 4] = ksh[i];
      const int jj = (i + (htid >> 4)) & 3;
      *(short4v*)&vt_lds[vd4 + jj][vkey4] = vsh[i];
    }
  };

  f32x4 acc[4];
#pragma unroll
  for (int i = 0; i < 4; ++i) acc[i] = (f32x4){0.f, 0.f, 0.f, 0.f};
  float m_run = -INFINITY;
  float l_run = 0.f;

  // prologue: tile 0 staged; mask(0) in flight
  load_kv(0);
  load_m(0);
  cvt_kv();
  write_kv();
  __syncthreads();

  for (int t = 0; t < NT_H; ++t) {
    const bool has_next = (t + 1 < NT_H);
    if (has_next) load_kv(t + 1);        // issue early; in flight through compute
    __builtin_amdgcn_sched_barrier(0);   // PIN: no sinking

    // ---- S^T = K Q^T : C row = key = f*16+g*4+r, col = q = c
    f32x4 sc[4];
#pragma unroll
    for (int f = 0; f < 4; ++f) {
      f32x4 a = (f32x4){0.f, 0.f, 0.f, 0.f};
#pragma unroll
      for (int ks = 0; ks < 2; ++ks) {
        bf16x8 kf = *(const bf16x8*)&k_lds[f * 16 + c][ks * 32 + g * 8];
        a = __builtin_amdgcn_mfma_f32_16x16x32_bf16(kf, qf[ks], a, 0, 0, 0);
      }
      sc[f] = a;
    }

    // ---- mask + scale into log2 domain (direct int4 selects, no packing;
    //      mask loads are older than kv(t+1) -> wait doesn't drain them)
#pragma unroll
    for (int f = 0; f < 4; ++f) {
      const int4 mm = mr[f];
      sc[f][0] = mm.x ? NEG : sc[f][0] * SC2;
      sc[f][1] = mm.y ? NEG : sc[f][1] * SC2;
      sc[f][2] = mm.z ? NEG : sc[f][2] * SC2;
      sc[f][3] = mm.w ? NEG : sc[f][3] * SC2;
    }
    if (has_next) load_m(t + 1);         // refill mask regs (0.5-tile cover)
    __builtin_amdgcn_sched_barrier(0);

    // ---- online softmax with defer-max
    float xl = sc[0][0];
#pragma unroll
    for (int f = 0; f < 4; ++f)
#pragma unroll
      for (int r = 0; r < 4; ++r) xl = fmaxf(xl, sc[f][r]);
    if (!__all(xl <= m_run + THR)) {
      float x = fmaxf(xl, __shfl_xor(xl, 16, 64));
      x = fmaxf(x, __shfl_xor(x, 32, 64));
      const float m_new = fmaxf(m_run, x);
      const float alpha = exp2f(m_run - m_new);
      l_run *= alpha;
      float ar[4];
#pragma unroll
      for (int r = 0; r < 4; ++r)
        ar[r] = __shfl(alpha, (lane & 48) | (g * 4 + r), 64);
#pragma unroll
      for (int fd = 0; fd < 4; ++fd)
#pragma unroll
        for (int r = 0; r < 4; ++r) acc[fd][r] *= ar[r];
      m_run = m_new;
    }
    float s = 0.f;
#pragma unroll
    for (int f = 0; f < 4; ++f)
#pragma unroll
      for (int r = 0; r < 4; ++r) {
        const float p = exp2f(sc[f][r] - m_run);
        sc[f][r] = p;
        s += p;
      }
    l_run += s;

    // ---- P relayout C->A in-register (two matchings, verified R10/R12/R13)
    unsigned int pd[4][2];
#pragma unroll
    for (int f = 0; f < 4; ++f) {
      pd[f][0] = pk2(sc[f][0], sc[f][1]);
      pd[f][1] = pk2(sc[f][2], sc[f][3]);
    }
    const int rev2 = ((g & 1) << 1) | (g >> 1);
    const int srcA = rev2 * 16 + c;
    const int srcB = srcA ^ 16;
    const bool podd = (g & 1) != 0;
    const bool gh   = (g >= 2);
    unsigned int d0[4], d1[4];
#pragma unroll
    for (int k = 0; k < 4; ++k) {
      const int fb = 2 * (k >> 1);
      const int hh = k & 1;
      const unsigned int pubA = podd ? pd[fb + 1][hh] : pd[fb + 0][hh];
      const unsigned int pubB = podd ? pd[fb + 0][hh] : pd[fb + 1][hh];
      const unsigned int rvA = (unsigned int)__shfl((int)pubA, srcA, 64);
      const unsigned int rvB = (unsigned int)__shfl((int)pubB, srcB, 64);
      if (k < 2) {
        if (gh) { d0[2 + hh] = rvA; d0[hh] = rvB; }
        else    { d0[hh] = rvA; d0[2 + hh] = rvB; }
      } else {
        if (gh) { d1[2 + hh] = rvA; d1[hh] = rvB; }
        else    { d1[hh] = rvA; d1[2 + hh] = rvB; }
      }
    }
    bf16x8 pa0, pa1;
    __builtin_memcpy(&pa0, d0, 16);
    __builtin_memcpy(&pa1, d1, 16);

    // ---- O += P V
#pragma unroll
    for (int fd = 0; fd < 4; ++fd) {
      bf16x8 vb0 = *(const bf16x8*)&vt_lds[fd * 16 + c][g * 8];
      acc[fd] = __builtin_amdgcn_mfma_f32_16x16x32_bf16(pa0, vb0, acc[fd], 0, 0, 0);
      bf16x8 vb1 = *(const bf16x8*)&vt_lds[fd * 16 + c][32 + g * 8];
      acc[fd] = __builtin_amdgcn_mfma_f32_16x16x32_bf16(pa1, vb1, acc[fd], 0, 0, 0);
    }

    // ---- T14 tail: cvt (waits kv(t+1) arrival, overlaps MFMA drain),
    //      then a SHORT write-only barrier window
    if (has_next) {
      cvt_kv();
      __syncthreads();    // readers of tile t done
      write_kv();
      __syncthreads();    // tile t+1 published
    }
  }

  // ==== combine the two key-halves in-block (reuse K/V LDS) ====
  float l = l_run;
  l += __shfl_xor(l, 16, 64);
  l += __shfl_xor(l, 32, 64);

  __syncthreads();                      // all compute done; LDS reusable
  f32x4* cacc = (f32x4*)smem;           // 16 KB scratch
  float2* cml = (float2*)(smem + 2 * HALF_LDS);
  if (half == 1) {
#pragma unroll
    for (int fd = 0; fd < 4; ++fd)
      cacc[(w4 * 64 + lane) * 4 + fd] = acc[fd];
    if (g == 0) cml[w4 * 16 + c] = make_float2(m_run, l);
  }
  __syncthreads();
  if (half == 0) {
    const float2 mlB = cml[w4 * 16 + c];
    const float Mx = fmaxf(m_run, mlB.x);
    const float wA = exp2f(m_run - Mx);
    const float wB = exp2f(mlB.x - Mx);
    const float li = 1.0f / (wA * l + wB * mlB.y);
    float arA[4], arB[4], lr[4];
#pragma unroll
    for (int r = 0; r < 4; ++r) {
      const int src = (lane & 48) | (g * 4 + r);
      arA[r] = __shfl(wA, src, 64);
      arB[r] = __shfl(wB, src, 64);
      lr[r]  = __shfl(li, src, 64);
    }
    float* orow = O + ((size_t)b * L_ + q0 + w4 * 16 + g * 4) * D_;
#pragma unroll
    for (int fd = 0; fd < 4; ++fd) {
      const f32x4 ab = cacc[(w4 * 64 + lane) * 4 + fd];
#pragma unroll
      for (int r = 0; r < 4; ++r)
        orow[(size_t)r * D_ + fd * 16 + c] =
            (arA[r] * acc[fd][r] + arB[r] * ab[r]) * lr[r];
    }
  }
}

extern "C" void kernel_launch(void* const* d_in, const int* in_sizes, int n_in,
                              void* d_out, int out_size, void* d_ws, size_t ws_size,
                              hipStream_t stream) {
  const float* q = (const float*)d_in[0];
  const float* k = (const float*)d_in[1];
  const float* v = (const float*)d_in[2];
  const int* m = (const int*)d_in[3]; // jax bool shipped as int32
  float* o = (float*)d_out;
  dim3 grid(L_ / QBLK, B_);
  attn_fwd<<<grid, 512, 0, stream>>>(q, k, v, m, o);
}